// Round 16
// baseline (117.840 us; speedup 1.0000x reference)
//
#include <hip/hip_runtime.h>
#include <stdint.h>

#define B_     4
#define A_     9
#define H_     50
#define W_     76
#define HW_    (H_ * W_)         // 3800
#define N_     (HW_ * A_)        // 34200
#define PRE_   6000
#define POST_  300
#define NBIN   16384
#define BINOFF 0xC000
#define SKCAP  8192
#define ACTMAX 256
#define KCAP   256               // register-rank cap (mean bucket ~134)
#define NB_    94                // ceil(PRE_/64)

// generate_anchors(16) precomputed (exact, verified against the numpy code)
__constant__ float c_anchors[9][4] = {
    { -84.f,  -40.f,  99.f,  55.f},
    {-176.f,  -88.f, 191.f, 103.f},
    {-360.f, -184.f, 375.f, 199.f},
    { -56.f,  -56.f,  71.f,  71.f},
    {-120.f, -120.f, 135.f, 135.f},
    {-248.f, -248.f, 263.f, 263.f},
    { -36.f,  -80.f,  51.f,  95.f},
    { -80.f, -168.f,  95.f, 183.f},
    {-168.f, -344.f, 183.f, 359.f},
};

// scores in [0,1) -> bin = top16(~score_bits) - 0xC000, clamped (monotone; exactness is
// restored by full-key rank within bucket in the fixup phase).
__device__ __forceinline__ int sb_bin(unsigned int sb) {
    int bin = (int)((~sb) >> 16) - BINOFF;
    return bin < 0 ? 0 : bin;
}

// box decode exactly in the reference op order; no FMA contraction
__device__ __forceinline__ void compute_box(int b, unsigned int n,
                                            const float* __restrict__ deltas,
                                            const float* __restrict__ im_info,
                                            float box[4]) {
#pragma clang fp contract(off)
    int a   = (int)(n % A_);
    int pos = (int)(n / A_);
    int w   = pos % W_;
    int h   = pos / W_;
    float a0 = c_anchors[a][0] + (float)(w * 16);
    float a1 = c_anchors[a][1] + (float)(h * 16);
    float a2 = c_anchors[a][2] + (float)(w * 16);
    float a3 = c_anchors[a][3] + (float)(h * 16);
    float wa  = a2 - a0 + 1.f;
    float ha  = a3 - a1 + 1.f;
    float cxa = a0 + 0.5f * wa;
    float cya = a1 + 0.5f * ha;
    int base = ((b * 4 * A_ + a * 4) * H_ + h) * W_ + w;
    const int chs = HW_;
    float dx = deltas[base];
    float dy = deltas[base + chs];
    float dw = deltas[base + 2 * chs];
    float dh = deltas[base + 3 * chs];
    float pcx = dx * wa + cxa;
    float pcy = dy * ha + cya;
    float pw  = expf(dw) * wa;
    float ph  = expf(dh) * ha;
    float x1 = pcx - 0.5f * pw;
    float y1 = pcy - 0.5f * ph;
    float x2 = pcx + 0.5f * pw;
    float y2 = pcy + 0.5f * ph;
    float imh = im_info[b * 3 + 0], imw = im_info[b * 3 + 1];
    x1 = fminf(fmaxf(x1, 0.f), imw - 1.f);
    x2 = fminf(fmaxf(x2, 0.f), imw - 1.f);
    y1 = fminf(fmaxf(y1, 0.f), imh - 1.f);
    y2 = fminf(fmaxf(y2, 0.f), imh - 1.f);
    box[0] = x1; box[1] = y1; box[2] = x2; box[3] = y2;
}

// ---- kernel 1: hist + prefix + scatter + bucket-rank + decode, ONE block per image.
//      All intermediates (hist/prefix, keys, active list) live in LDS; only the
//      sorted+decoded boxes go to global. ~133 KB static LDS (1 wg/CU; grid = 4).
__global__ __launch_bounds__(1024) void k_hps_fx(const float* __restrict__ scores,
                                                 const float* __restrict__ deltas,
                                                 const float* __restrict__ im_info,
                                                 float* __restrict__ sboxes) {
    const int b = blockIdx.x, tid = threadIdx.x;
    const int lane = tid & 63, wid = tid >> 6;
    __shared__ unsigned int LHIST[NBIN];            // 64 KB: hist -> prefix -> working
    __shared__ unsigned long long SKEY[SKCAP];      // 64 KB: scattered keys
    __shared__ unsigned int s_wsum[16];
    __shared__ unsigned int s_aA[ACTMAX];
    __shared__ unsigned int s_aB[ACTMAX];
    __shared__ int s_actn, s_binhi;

    for (int i = tid; i < NBIN; i += 1024) LHIST[i] = 0u;
    if (tid == 0) { s_actn = 0; s_binhi = 0; }
    __syncthreads();

    // P1: LDS histogram (coalesced score reads)
    const float* sc = scores + (size_t)((b * 2 * A_) + A_) * HW_;
    for (int i = tid; i < N_; i += 1024) {
        unsigned int sb = __float_as_uint(sc[i]);
        atomicAdd(&LHIST[sb_bin(sb)], 1u);
    }
    __syncthreads();

    // P2: in-place exclusive prefix (16 bins/thread, hierarchical shfl scan),
    //     active-bucket list, bin_hi (prefix monotone -> active bins = [0, bin_hi])
    {
        int base0 = tid * 16;
        unsigned int sum = 0;
        for (int q = 0; q < 16; ++q) sum += LHIST[base0 + q];
        unsigned int inc = sum;
#pragma unroll
        for (int off = 1; off < 64; off <<= 1) {
            unsigned int t = __shfl_up(inc, off);
            if (lane >= off) inc += t;
        }
        if (lane == 63) s_wsum[wid] = inc;
        __syncthreads();
        unsigned int wbase = 0;
        for (int wq = 0; wq < wid; ++wq) wbase += s_wsum[wq];
        unsigned int run = wbase + inc - sum;     // exclusive prefix of this thread's bins
        int mybinhi = -1;
        for (int q = 0; q < 16; ++q) {
            unsigned int c = LHIST[base0 + q];
            LHIST[base0 + q] = run;
            if (run < (unsigned int)PRE_) {
                mybinhi = base0 + q;
                if (c > 0) {
                    int pos = atomicAdd(&s_actn, 1);
                    if (pos < ACTMAX) {
                        s_aA[pos] = run;
                        s_aB[pos] = ((unsigned int)(base0 + q) << 16) | (c & 0xffffu);
                    }
                }
            }
            run += c;
        }
        if (mybinhi >= 0) atomicMax(&s_binhi, mybinhi);
    }
    __syncthreads();

    // P3: scatter keys of active bins into LDS slot ranges (arrival order)
    {
        int binhi = s_binhi;
        for (int i = tid; i < N_; i += 1024) {
            unsigned int sb = __float_as_uint(sc[i]);
            int bin = sb_bin(sb);
            if (bin <= binhi) {
                unsigned int slot = atomicAdd(&LHIST[bin], 1u);
                if (slot < SKCAP) {
                    int a = i / HW_, r = i - a * HW_;
                    unsigned int n = (unsigned int)(r * A_ + a);
                    SKEY[slot] =
                        (((unsigned long long)(~sb)) << 32) | (unsigned long long)n;
                }
            }
        }
    }
    __syncthreads();

    // P4: per-wave bucket rank (in registers, round-11 proven) + decode into global
    {
        int nact = s_actn; if (nact > ACTMAX) nact = ACTMAX;
        float4* sb4 = (float4*)sboxes;
        for (int t = wid; t < nact; t += 16) {
            unsigned int start = s_aA[t];
            unsigned int m     = s_aB[t] & 0xffffu;
            if (start + m > SKCAP) m = SKCAP - start;
            const unsigned long long* kb = SKEY + start;
            if (m <= KCAP) {
                unsigned long long kreg[4];
                unsigned int rnk[4];
#pragma unroll
                for (int q = 0; q < 4; ++q) {
                    unsigned int e = (unsigned int)lane + q * 64u;
                    kreg[q] = (e < m) ? kb[e] : ~0ull;
                    rnk[q] = 0;
                }
#pragma unroll
                for (int q2 = 0; q2 < 4; ++q2) {
                    int base2 = q2 * 64;
                    if (base2 >= (int)m) break;
                    unsigned long long kq = kreg[q2];
                    int lim = (int)m - base2; if (lim > 64) lim = 64;
                    for (int l = 0; l < lim; ++l) {
                        unsigned long long ki = __shfl(kq, l);
#pragma unroll
                        for (int q = 0; q < 4; ++q) rnk[q] += (ki < kreg[q]) ? 1u : 0u;
                    }
                }
#pragma unroll
                for (int q = 0; q < 4; ++q) {
                    unsigned int e = (unsigned int)lane + q * 64u;
                    if (e < m) {
                        unsigned int pos = start + rnk[q];
                        if (pos < (unsigned int)PRE_) {
                            unsigned int n = (unsigned int)(kreg[q] & 0xffffffffull);
                            float box[4];
                            compute_box(b, n, deltas, im_info, box);
                            sb4[b * PRE_ + pos] = make_float4(box[0], box[1], box[2], box[3]);
                        }
                    }
                }
            } else {   // exact fallback for pathological bucket sizes
                for (unsigned int e = lane; e < m; e += 64) {
                    unsigned long long k = kb[e];
                    unsigned int r = 0;
                    for (unsigned int i2 = 0; i2 < m; ++i2) r += (kb[i2] < k) ? 1u : 0u;
                    unsigned int pos = start + r;
                    if (pos < (unsigned int)PRE_) {
                        unsigned int n = (unsigned int)(k & 0xffffffffull);
                        float box[4];
                        compute_box(b, n, deltas, im_info, box);
                        sb4[b * PRE_ + pos] = make_float4(box[0], box[1], box[2], box[3]);
                    }
                }
            }
        }
    }
}

__device__ __forceinline__ bool iou_gt(float4 p, float pa, float4 q, float qa) {
    float iw = fminf(p.z, q.z) - fmaxf(p.x, q.x) + 1.f;
    float ih = fminf(p.w, q.w) - fmaxf(p.y, q.y) + 1.f;
    iw = fmaxf(iw, 0.f); ih = fmaxf(ih, 0.f);
    float inter = iw * ih;
    float iou = inter / ((pa + qa) - inter);
    return iou > 0.7f;
}

// ---- kernel 2: exact greedy NMS, pipelined (round-7 structure) with IN-LOOP mask
//      generation (round-15 proven). Triple-buffered diagonal mask tiles in LDS.
__global__ __launch_bounds__(1024) void k_nms(const float* __restrict__ sboxes,
                                              float* __restrict__ out) {
    int b = blockIdx.x;
    int tid = threadIdx.x;
    int lane = tid & 63;
    int wave = tid >> 6;                     // 0..15
    __shared__ float4 s_box[POST_ + 64];
    __shared__ float  s_ar [POST_ + 64];
    __shared__ unsigned long long s_pend[2][16];
    __shared__ unsigned long long s_mtile[3][64];   // triple-buffered mask tiles
    __shared__ int s_cnt[2];
    __shared__ int s_final;
    if (tid < 32) ((unsigned long long*)s_pend)[tid] = 0ull;
    if (tid < 2) s_cnt[tid] = 0;
    if (tid == 0) s_final = 0;

    const float4* bb = (const float4*)sboxes + b * PRE_;
    float* ob = out + b * POST_ * 5;

    // prologue: build mask tiles for blocks 0 (waves 0-7) and 1 (waves 8-15)
    {
        int blk01 = (wave < 8) ? 0 : 1;
        int wrel = wave & 7;
        float4 vb = bb[blk01 * 64 + lane];
        float ab = ((vb.z - vb.x) + 1.f) * ((vb.w - vb.y) + 1.f);
        for (int r = wrel * 8; r < wrel * 8 + 8; ++r) {
            float4 p;
            p.x = __shfl(vb.x, r); p.y = __shfl(vb.y, r);
            p.z = __shfl(vb.z, r); p.w = __shfl(vb.w, r);
            float pa = __shfl(ab, r);
            unsigned long long bal = __ballot((lane > r) && iou_gt(p, pa, vb, ab));
            if (lane == 0) s_mtile[blk01][r] = bal;
        }
    }
    // register prefetch: wave0 holds block 0; waves 1-15 hold block 1
    float4 vme;
    if (wave == 0) vme = bb[lane];
    else           vme = bb[64 + lane];
    __syncthreads();

    for (int k = 0; k < NB_; ++k) {
        int Cm1 = s_cnt[(k + 1) & 1];         // kept count through block k-1
        if (Cm1 >= POST_) break;
        if (wave == 0) {
            int idx = k * 64 + lane;
            bool valid = idx < PRE_;
            float4 v = vme;
            unsigned long long row = s_mtile[k % 3][lane];
            if (k + 1 < NB_) {                 // prefetch block k+1
                int nidx = (k + 1) * 64 + lane;
                vme = bb[nidx < PRE_ ? nidx : PRE_ - 1];
            }
            float area = ((v.z - v.x) + 1.f) * ((v.w - v.y) + 1.f);
            int Cm2 = s_cnt[k & 1];           // kept count through block k-2
            bool sup = !valid;
            int kk = Cm2;                      // delta: keeps added by block k-1
            for (; kk + 1 < Cm1; kk += 2) {
                float4 k0 = s_box[kk],   k1 = s_box[kk + 1];
                float  r0 = s_ar [kk],   r1 = s_ar [kk + 1];
                sup = sup | iou_gt(v, area, k0, r0) | iou_gt(v, area, k1, r1);
            }
            for (; kk < Cm1; ++kk)
                sup = sup | iou_gt(v, area, s_box[kk], s_ar[kk]);
            unsigned long long supm = __ballot(sup);
            const unsigned long long* pnd = s_pend[k & 1];
#pragma unroll
            for (int w2 = 1; w2 < 16; ++w2) supm |= pnd[w2];
            unsigned int rlo = (unsigned int)row;
            unsigned int rhi = (unsigned int)(row >> 32);
            unsigned long long alive = ~supm;
            unsigned long long keepm = 0ull;
            while (alive) {
                int i = __builtin_ctzll(alive);     // uniform across wave 0
                keepm |= (1ull << i);
                alive &= ~(1ull << i);
                unsigned long long mlo = (unsigned int)__builtin_amdgcn_readlane((int)rlo, i);
                unsigned long long mhi = (unsigned int)__builtin_amdgcn_readlane((int)rhi, i);
                alive &= ~((mhi << 32) | mlo);
            }
            if ((keepm >> lane) & 1ull) {
                int my = Cm1 + __builtin_popcountll(keepm & ((1ull << lane) - 1ull));
                s_box[my] = v;
                s_ar [my] = area;
                if (my < POST_) {
                    ob[my * 5 + 0] = (float)b;
                    ob[my * 5 + 1] = v.x; ob[my * 5 + 2] = v.y;
                    ob[my * 5 + 3] = v.z; ob[my * 5 + 4] = v.w;
                }
            }
            if (lane == 0) {
                int nc = Cm1 + __builtin_popcountll(keepm);
                s_cnt[k & 1] = nc;
                s_final = nc;
            }
        } else if (k + 1 < NB_) {
            // phase-a for block k+1 vs kept[0..Cm1), stride 15, unrolled x4
            int jdx = (k + 1) * 64 + lane;
            bool valid2 = jdx < PRE_;
            float4 v2 = vme;
            if (k + 2 < NB_) {                 // prefetch block k+2
                int nj = (k + 2) * 64 + lane;
                vme = bb[nj < PRE_ ? nj : PRE_ - 1];
            }
            float area2 = ((v2.z - v2.x) + 1.f) * ((v2.w - v2.y) + 1.f);
            bool sup2 = !valid2;
            int kk = wave - 1;
            for (; kk + 45 < Cm1; kk += 60) {
                float4 k0 = s_box[kk],      k1 = s_box[kk + 15];
                float4 k2 = s_box[kk + 30], k3 = s_box[kk + 45];
                float  r0 = s_ar [kk],      r1 = s_ar [kk + 15];
                float  r2 = s_ar [kk + 30], r3 = s_ar [kk + 45];
                sup2 = sup2 | iou_gt(v2, area2, k0, r0) | iou_gt(v2, area2, k1, r1)
                            | iou_gt(v2, area2, k2, r2) | iou_gt(v2, area2, k3, r3);
            }
            for (; kk < Cm1; kk += 15)
                sup2 = sup2 | iou_gt(v2, area2, s_box[kk], s_ar[kk]);
            unsigned long long bal = __ballot(sup2);
            if (lane == 0) s_pend[(k + 1) & 1][wave] = bal;
            // build mask tile for block k+2 (vme holds its boxes) into slot (k+2)%3
            if (k + 2 < NB_) {
                float amex = ((vme.z - vme.x) + 1.f) * ((vme.w - vme.y) + 1.f);
                int slot = (k + 2) % 3;
                for (int r = wave - 1; r < 64; r += 15) {
                    float4 p;
                    p.x = __shfl(vme.x, r); p.y = __shfl(vme.y, r);
                    p.z = __shfl(vme.z, r); p.w = __shfl(vme.w, r);
                    float pa = __shfl(amex, r);
                    unsigned long long mb = __ballot((lane > r) && iou_gt(p, pa, vme, amex));
                    if (lane == 0) s_mtile[slot][r] = mb;
                }
            }
        }
        __syncthreads();
    }
    __syncthreads();
    int kept = s_final;
    int start = kept < POST_ ? kept : POST_;
    for (int r = start + tid; r < POST_; r += 1024) {
        ob[r * 5 + 0] = (float)b;
        ob[r * 5 + 1] = 0.f; ob[r * 5 + 2] = 0.f;
        ob[r * 5 + 3] = 0.f; ob[r * 5 + 4] = 0.f;
    }
}

extern "C" void kernel_launch(void* const* d_in, const int* in_sizes, int n_in,
                              void* d_out, int out_size, void* d_ws, size_t ws_size,
                              hipStream_t stream) {
    const float* scores  = (const float*)d_in[0];
    const float* deltas  = (const float*)d_in[1];
    const float* im_info = (const float*)d_in[2];
    float* out = (float*)d_out;

    float* sbx = (float*)d_ws;   // B*PRE*4 floats = 384,000 bytes

    k_hps_fx<<<B_, 1024, 0, stream>>>(scores, deltas, im_info, sbx);
    k_nms<<<B_, 1024, 0, stream>>>(sbx, out);
}

// Round 17
// 80.528 us; speedup vs baseline: 1.4634x; 1.4634x over previous
//
#include <hip/hip_runtime.h>
#include <stdint.h>

#define B_     4
#define A_     9
#define H_     50
#define W_     76
#define HW_    (H_ * W_)         // 3800
#define N_     (HW_ * A_)        // 34200
#define PRE_   6000
#define POST_  300
#define NBIN   16384
#define BINOFF 0xC000
#define SKCAP  8192
#define ACTMAX 256
#define FXCAP  2048
#define FXGRID 64
#define NB_    94                // ceil(PRE_/64)

// generate_anchors(16) precomputed (exact, verified against the numpy code)
__constant__ float c_anchors[9][4] = {
    { -84.f,  -40.f,  99.f,  55.f},
    {-176.f,  -88.f, 191.f, 103.f},
    {-360.f, -184.f, 375.f, 199.f},
    { -56.f,  -56.f,  71.f,  71.f},
    {-120.f, -120.f, 135.f, 135.f},
    {-248.f, -248.f, 263.f, 263.f},
    { -36.f,  -80.f,  51.f,  95.f},
    { -80.f, -168.f,  95.f, 183.f},
    {-168.f, -344.f, 183.f, 359.f},
};

// scores in [0,1) -> bin = top16(~score_bits) - 0xC000, clamped (monotone; exactness is
// restored by full-key rank within bucket in k_fixup).
__device__ __forceinline__ int sb_bin(unsigned int sb) {
    int bin = (int)((~sb) >> 16) - BINOFF;
    return bin < 0 ? 0 : bin;
}

// ---- kernel 1: fused LDS histogram + prefix + scatter, ONE block per image.
//      (per-image dependency -> single workgroup, only __syncthreads needed).
//      Writes skeys + active-bucket list to global. Scores read as float4.
__global__ __launch_bounds__(1024) void k_hps(const float* __restrict__ scores,
                                              unsigned long long* __restrict__ skeys,
                                              unsigned int* __restrict__ actA,
                                              unsigned int* __restrict__ actB,
                                              unsigned int* __restrict__ actcnt) {
    const int b = blockIdx.x, tid = threadIdx.x;
    const int lane = tid & 63, wid = tid >> 6;
    __shared__ unsigned int LHIST[NBIN];    // 64 KB: hist -> exclusive prefix -> working
    __shared__ unsigned int s_wsum[16];
    __shared__ unsigned int s_aA[ACTMAX];
    __shared__ unsigned int s_aB[ACTMAX];
    __shared__ int s_actn, s_binhi;

    for (int i = tid; i < NBIN; i += 1024) LHIST[i] = 0u;
    if (tid == 0) { s_actn = 0; s_binhi = 0; }
    __syncthreads();

    // P1: LDS histogram (float4-vectorized coalesced score reads; N_ % 4 == 0,
    //     plane offset (b*18+9)*3800 floats = multiple of 16 bytes)
    const float* sc = scores + (size_t)((b * 2 * A_) + A_) * HW_;
    const float4* sc4 = (const float4*)sc;
    for (int i = tid; i < N_ / 4; i += 1024) {
        float4 s4 = sc4[i];
        atomicAdd(&LHIST[sb_bin(__float_as_uint(s4.x))], 1u);
        atomicAdd(&LHIST[sb_bin(__float_as_uint(s4.y))], 1u);
        atomicAdd(&LHIST[sb_bin(__float_as_uint(s4.z))], 1u);
        atomicAdd(&LHIST[sb_bin(__float_as_uint(s4.w))], 1u);
    }
    __syncthreads();

    // P2: in-place exclusive prefix (16 bins/thread, hierarchical shfl scan),
    //     active-bucket list, bin_hi (prefix monotone -> active bins = [0, bin_hi])
    {
        int base0 = tid * 16;
        unsigned int sum = 0;
        for (int q = 0; q < 16; ++q) sum += LHIST[base0 + q];
        unsigned int inc = sum;
#pragma unroll
        for (int off = 1; off < 64; off <<= 1) {
            unsigned int t = __shfl_up(inc, off);
            if (lane >= off) inc += t;
        }
        if (lane == 63) s_wsum[wid] = inc;
        __syncthreads();
        unsigned int wbase = 0;
        for (int wq = 0; wq < wid; ++wq) wbase += s_wsum[wq];
        unsigned int run = wbase + inc - sum;     // exclusive prefix of this thread's bins
        int mybinhi = -1;
        for (int q = 0; q < 16; ++q) {
            unsigned int c = LHIST[base0 + q];
            LHIST[base0 + q] = run;
            if (run < (unsigned int)PRE_) {
                mybinhi = base0 + q;
                if (c > 0) {
                    int pos = atomicAdd(&s_actn, 1);
                    if (pos < ACTMAX) {
                        s_aA[pos] = run;
                        s_aB[pos] = ((unsigned int)(base0 + q) << 16) | (c & 0xffffu);
                    }
                }
            }
            run += c;
        }
        if (mybinhi >= 0) atomicMax(&s_binhi, mybinhi);
    }
    __syncthreads();

    // P3: scatter keys of active bins to global slot ranges (arrival order)
    {
        int binhi = s_binhi;
        for (int i = tid; i < N_ / 4; i += 1024) {
            float4 s4 = sc4[i];
            float ss[4] = {s4.x, s4.y, s4.z, s4.w};
#pragma unroll
            for (int k2 = 0; k2 < 4; ++k2) {
                unsigned int sb = __float_as_uint(ss[k2]);
                int bin = sb_bin(sb);
                if (bin <= binhi) {
                    unsigned int slot = atomicAdd(&LHIST[bin], 1u);
                    if (slot < SKCAP) {
                        int i0 = i * 4 + k2;
                        int a = i0 / HW_, r = i0 - a * HW_;
                        unsigned int n = (unsigned int)(r * A_ + a);
                        skeys[b * SKCAP + slot] =
                            (((unsigned long long)(~sb)) << 32) | (unsigned long long)n;
                    }
                }
            }
        }
    }
    // export active-bucket list (written in P2; sync above orders it)
    int n = s_actn; if (n > ACTMAX) n = ACTMAX;
    for (int i = tid; i < n; i += 1024) {
        actA[b * ACTMAX + i] = s_aA[i];
        actB[b * ACTMAX + i] = s_aB[i];
    }
    if (tid == 0) actcnt[b] = (unsigned int)n;
}

// box decode exactly in the reference op order; no FMA contraction
__device__ __forceinline__ void compute_box(int b, unsigned int n,
                                            const float* __restrict__ deltas,
                                            const float* __restrict__ im_info,
                                            float box[4]) {
#pragma clang fp contract(off)
    int a   = (int)(n % A_);
    int pos = (int)(n / A_);
    int w   = pos % W_;
    int h   = pos / W_;
    float a0 = c_anchors[a][0] + (float)(w * 16);
    float a1 = c_anchors[a][1] + (float)(h * 16);
    float a2 = c_anchors[a][2] + (float)(w * 16);
    float a3 = c_anchors[a][3] + (float)(h * 16);
    float wa  = a2 - a0 + 1.f;
    float ha  = a3 - a1 + 1.f;
    float cxa = a0 + 0.5f * wa;
    float cya = a1 + 0.5f * ha;
    int base = ((b * 4 * A_ + a * 4) * H_ + h) * W_ + w;
    const int chs = HW_;
    float dx = deltas[base];
    float dy = deltas[base + chs];
    float dw = deltas[base + 2 * chs];
    float dh = deltas[base + 3 * chs];
    float pcx = dx * wa + cxa;
    float pcy = dy * ha + cya;
    float pw  = expf(dw) * wa;
    float ph  = expf(dh) * ha;
    float x1 = pcx - 0.5f * pw;
    float y1 = pcy - 0.5f * ph;
    float x2 = pcx + 0.5f * pw;
    float y2 = pcy + 0.5f * ph;
    float imh = im_info[b * 3 + 0], imw = im_info[b * 3 + 1];
    x1 = fminf(fmaxf(x1, 0.f), imw - 1.f);
    x2 = fminf(fmaxf(x2, 0.f), imw - 1.f);
    y1 = fminf(fmaxf(y1, 0.f), imh - 1.f);
    y2 = fminf(fmaxf(y2, 0.f), imh - 1.f);
    box[0] = x1; box[1] = y1; box[2] = x2; box[3] = y2;
}

// ---- kernel 2: per-bucket exact rank-by-counting + box decode into final sorted slot.
//      WIDE kernel (scattered delta gather needs chip-wide MLP). Grid-stride over
//      buckets so the grid stays small (64 x B).
__global__ __launch_bounds__(256) void k_fixup(const unsigned long long* __restrict__ skeys,
                                               const unsigned int* __restrict__ actA,
                                               const unsigned int* __restrict__ actB,
                                               const unsigned int* __restrict__ actcnt,
                                               const float* __restrict__ deltas,
                                               const float* __restrict__ im_info,
                                               float* __restrict__ sboxes) {
    int b = blockIdx.y;
    unsigned int nact = actcnt[b];
    if (nact > ACTMAX) nact = ACTMAX;
    int tid = threadIdx.x;
    __shared__ unsigned long long lk[FXCAP];   // 16 KB
    float4* sb4 = (float4*)sboxes;
    for (unsigned int t = blockIdx.x; t < nact; t += FXGRID) {
        unsigned int start = actA[b * ACTMAX + t];
        unsigned int ab    = actB[b * ACTMAX + t];
        unsigned int cnt   = ab & 0xffffu;
        unsigned int m = cnt;
        if (start + m > SKCAP) m = SKCAP - start;
        if (m > FXCAP) m = FXCAP;
        for (unsigned int i = tid; i < m; i += 256) lk[i] = skeys[b * SKCAP + start + i];
        __syncthreads();
        for (unsigned int e = tid; e < m; e += 256) {
            unsigned long long k = lk[e];
            unsigned int r = 0;
            for (unsigned int i = 0; i < m; ++i) r += (lk[i] < k) ? 1u : 0u;
            unsigned int pos = start + r;
            if (pos < (unsigned int)PRE_) {
                unsigned int n = (unsigned int)(k & 0xffffffffull);
                float box[4];
                compute_box(b, n, deltas, im_info, box);
                sb4[b * PRE_ + pos] = make_float4(box[0], box[1], box[2], box[3]);
            }
        }
        __syncthreads();
    }
}

__device__ __forceinline__ bool iou_gt(float4 p, float pa, float4 q, float qa) {
    float iw = fminf(p.z, q.z) - fmaxf(p.x, q.x) + 1.f;
    float ih = fminf(p.w, q.w) - fmaxf(p.y, q.y) + 1.f;
    iw = fmaxf(iw, 0.f); ih = fmaxf(ih, 0.f);
    float inter = iw * ih;
    float iou = inter / ((pa + qa) - inter);
    return iou > 0.7f;
}

// ---- kernel 3: exact greedy NMS, pipelined (round-7 structure) with IN-LOOP mask
//      generation (round-15 proven). Triple-buffered diagonal mask tiles in LDS.
__global__ __launch_bounds__(1024) void k_nms(const float* __restrict__ sboxes,
                                              float* __restrict__ out) {
    int b = blockIdx.x;
    int tid = threadIdx.x;
    int lane = tid & 63;
    int wave = tid >> 6;                     // 0..15
    __shared__ float4 s_box[POST_ + 64];
    __shared__ float  s_ar [POST_ + 64];
    __shared__ unsigned long long s_pend[2][16];
    __shared__ unsigned long long s_mtile[3][64];   // triple-buffered mask tiles
    __shared__ int s_cnt[2];
    __shared__ int s_final;
    if (tid < 32) ((unsigned long long*)s_pend)[tid] = 0ull;
    if (tid < 2) s_cnt[tid] = 0;
    if (tid == 0) s_final = 0;

    const float4* bb = (const float4*)sboxes + b * PRE_;
    float* ob = out + b * POST_ * 5;

    // prologue: build mask tiles for blocks 0 (waves 0-7) and 1 (waves 8-15)
    {
        int blk01 = (wave < 8) ? 0 : 1;
        int wrel = wave & 7;
        float4 vb = bb[blk01 * 64 + lane];
        float ab = ((vb.z - vb.x) + 1.f) * ((vb.w - vb.y) + 1.f);
        for (int r = wrel * 8; r < wrel * 8 + 8; ++r) {
            float4 p;
            p.x = __shfl(vb.x, r); p.y = __shfl(vb.y, r);
            p.z = __shfl(vb.z, r); p.w = __shfl(vb.w, r);
            float pa = __shfl(ab, r);
            unsigned long long bal = __ballot((lane > r) && iou_gt(p, pa, vb, ab));
            if (lane == 0) s_mtile[blk01][r] = bal;
        }
    }
    // register prefetch: wave0 holds block 0; waves 1-15 hold block 1
    float4 vme;
    if (wave == 0) vme = bb[lane];
    else           vme = bb[64 + lane];
    __syncthreads();

    for (int k = 0; k < NB_; ++k) {
        int Cm1 = s_cnt[(k + 1) & 1];         // kept count through block k-1
        if (Cm1 >= POST_) break;
        if (wave == 0) {
            int idx = k * 64 + lane;
            bool valid = idx < PRE_;
            float4 v = vme;
            unsigned long long row = s_mtile[k % 3][lane];
            if (k + 1 < NB_) {                 // prefetch block k+1
                int nidx = (k + 1) * 64 + lane;
                vme = bb[nidx < PRE_ ? nidx : PRE_ - 1];
            }
            float area = ((v.z - v.x) + 1.f) * ((v.w - v.y) + 1.f);
            int Cm2 = s_cnt[k & 1];           // kept count through block k-2
            bool sup = !valid;
            int kk = Cm2;                      // delta: keeps added by block k-1
            for (; kk + 1 < Cm1; kk += 2) {
                float4 k0 = s_box[kk],   k1 = s_box[kk + 1];
                float  r0 = s_ar [kk],   r1 = s_ar [kk + 1];
                sup = sup | iou_gt(v, area, k0, r0) | iou_gt(v, area, k1, r1);
            }
            for (; kk < Cm1; ++kk)
                sup = sup | iou_gt(v, area, s_box[kk], s_ar[kk]);
            unsigned long long supm = __ballot(sup);
            const unsigned long long* pnd = s_pend[k & 1];
#pragma unroll
            for (int w2 = 1; w2 < 16; ++w2) supm |= pnd[w2];
            unsigned int rlo = (unsigned int)row;
            unsigned int rhi = (unsigned int)(row >> 32);
            unsigned long long alive = ~supm;
            unsigned long long keepm = 0ull;
            while (alive) {
                int i = __builtin_ctzll(alive);     // uniform across wave 0
                keepm |= (1ull << i);
                alive &= ~(1ull << i);
                unsigned long long mlo = (unsigned int)__builtin_amdgcn_readlane((int)rlo, i);
                unsigned long long mhi = (unsigned int)__builtin_amdgcn_readlane((int)rhi, i);
                alive &= ~((mhi << 32) | mlo);
            }
            if ((keepm >> lane) & 1ull) {
                int my = Cm1 + __builtin_popcountll(keepm & ((1ull << lane) - 1ull));
                s_box[my] = v;
                s_ar [my] = area;
                if (my < POST_) {
                    ob[my * 5 + 0] = (float)b;
                    ob[my * 5 + 1] = v.x; ob[my * 5 + 2] = v.y;
                    ob[my * 5 + 3] = v.z; ob[my * 5 + 4] = v.w;
                }
            }
            if (lane == 0) {
                int nc = Cm1 + __builtin_popcountll(keepm);
                s_cnt[k & 1] = nc;
                s_final = nc;
            }
        } else if (k + 1 < NB_) {
            // phase-a for block k+1 vs kept[0..Cm1), stride 15, unrolled x4
            int jdx = (k + 1) * 64 + lane;
            bool valid2 = jdx < PRE_;
            float4 v2 = vme;
            if (k + 2 < NB_) {                 // prefetch block k+2
                int nj = (k + 2) * 64 + lane;
                vme = bb[nj < PRE_ ? nj : PRE_ - 1];
            }
            float area2 = ((v2.z - v2.x) + 1.f) * ((v2.w - v2.y) + 1.f);
            bool sup2 = !valid2;
            int kk = wave - 1;
            for (; kk + 45 < Cm1; kk += 60) {
                float4 k0 = s_box[kk],      k1 = s_box[kk + 15];
                float4 k2 = s_box[kk + 30], k3 = s_box[kk + 45];
                float  r0 = s_ar [kk],      r1 = s_ar [kk + 15];
                float  r2 = s_ar [kk + 30], r3 = s_ar [kk + 45];
                sup2 = sup2 | iou_gt(v2, area2, k0, r0) | iou_gt(v2, area2, k1, r1)
                            | iou_gt(v2, area2, k2, r2) | iou_gt(v2, area2, k3, r3);
            }
            for (; kk < Cm1; kk += 15)
                sup2 = sup2 | iou_gt(v2, area2, s_box[kk], s_ar[kk]);
            unsigned long long bal = __ballot(sup2);
            if (lane == 0) s_pend[(k + 1) & 1][wave] = bal;
            // build mask tile for block k+2 (vme holds its boxes) into slot (k+2)%3
            if (k + 2 < NB_) {
                float amex = ((vme.z - vme.x) + 1.f) * ((vme.w - vme.y) + 1.f);
                int slot = (k + 2) % 3;
                for (int r = wave - 1; r < 64; r += 15) {
                    float4 p;
                    p.x = __shfl(vme.x, r); p.y = __shfl(vme.y, r);
                    p.z = __shfl(vme.z, r); p.w = __shfl(vme.w, r);
                    float pa = __shfl(amex, r);
                    unsigned long long mb = __ballot((lane > r) && iou_gt(p, pa, vme, amex));
                    if (lane == 0) s_mtile[slot][r] = mb;
                }
            }
        }
        __syncthreads();
    }
    __syncthreads();
    int kept = s_final;
    int start = kept < POST_ ? kept : POST_;
    for (int r = start + tid; r < POST_; r += 1024) {
        ob[r * 5 + 0] = (float)b;
        ob[r * 5 + 1] = 0.f; ob[r * 5 + 2] = 0.f;
        ob[r * 5 + 3] = 0.f; ob[r * 5 + 4] = 0.f;
    }
}

extern "C" void kernel_launch(void* const* d_in, const int* in_sizes, int n_in,
                              void* d_out, int out_size, void* d_ws, size_t ws_size,
                              hipStream_t stream) {
    const float* scores  = (const float*)d_in[0];
    const float* deltas  = (const float*)d_in[1];
    const float* im_info = (const float*)d_in[2];
    float* out = (float*)d_out;

    char* ws = (char*)d_ws;
    unsigned long long* skeys  = (unsigned long long*)(ws);            // 262,144
    unsigned int*       actA   = (unsigned int*)      (ws + 262144);   //   4,096
    unsigned int*       actB   = (unsigned int*)      (ws + 266240);   //   4,096
    unsigned int*       actcnt = (unsigned int*)      (ws + 270336);   //      32
    float*              sbx    = (float*)             (ws + 270368);   // 384,000

    k_hps<<<B_, 1024, 0, stream>>>(scores, skeys, actA, actB, actcnt);
    dim3 fgrid(FXGRID, B_);
    k_fixup<<<fgrid, 256, 0, stream>>>(skeys, actA, actB, actcnt, deltas, im_info, sbx);
    k_nms<<<B_, 1024, 0, stream>>>(sbx, out);
}

// Round 18
// 80.404 us; speedup vs baseline: 1.4656x; 1.0015x over previous
//
#include <hip/hip_runtime.h>
#include <stdint.h>

#define B_     4
#define A_     9
#define H_     50
#define W_     76
#define HW_    (H_ * W_)         // 3800
#define N_     (HW_ * A_)        // 34200
#define PRE_   6000
#define POST_  300
#define NBIN   16384
#define BINOFF 0xC000
#define SKCAP  8192
#define ACTMAX 256
#define FXCAP  2048
#define FXGRID 64
#define NB_    94                // ceil(PRE_/64)

// generate_anchors(16) precomputed (exact, verified against the numpy code)
__constant__ float c_anchors[9][4] = {
    { -84.f,  -40.f,  99.f,  55.f},
    {-176.f,  -88.f, 191.f, 103.f},
    {-360.f, -184.f, 375.f, 199.f},
    { -56.f,  -56.f,  71.f,  71.f},
    {-120.f, -120.f, 135.f, 135.f},
    {-248.f, -248.f, 263.f, 263.f},
    { -36.f,  -80.f,  51.f,  95.f},
    { -80.f, -168.f,  95.f, 183.f},
    {-168.f, -344.f, 183.f, 359.f},
};

// scores in [0,1) -> bin = top16(~score_bits) - 0xC000, clamped (monotone; exactness is
// restored by full-key rank within bucket in k_fixup).
__device__ __forceinline__ int sb_bin(unsigned int sb) {
    int bin = (int)((~sb) >> 16) - BINOFF;
    return bin < 0 ? 0 : bin;
}

// ---- kernel 1: fused LDS histogram + prefix + scatter, ONE block per image.
//      (per-image dependency -> single workgroup, only __syncthreads needed).
//      Writes skeys + active-bucket list to global. Scores read as float4.
__global__ __launch_bounds__(1024) void k_hps(const float* __restrict__ scores,
                                              unsigned long long* __restrict__ skeys,
                                              unsigned int* __restrict__ actA,
                                              unsigned int* __restrict__ actB,
                                              unsigned int* __restrict__ actcnt) {
    const int b = blockIdx.x, tid = threadIdx.x;
    const int lane = tid & 63, wid = tid >> 6;
    __shared__ unsigned int LHIST[NBIN];    // 64 KB: hist -> exclusive prefix -> working
    __shared__ unsigned int s_wsum[16];
    __shared__ unsigned int s_aA[ACTMAX];
    __shared__ unsigned int s_aB[ACTMAX];
    __shared__ int s_actn, s_binhi;

    for (int i = tid; i < NBIN; i += 1024) LHIST[i] = 0u;
    if (tid == 0) { s_actn = 0; s_binhi = 0; }
    __syncthreads();

    // P1: LDS histogram (float4-vectorized coalesced score reads)
    const float* sc = scores + (size_t)((b * 2 * A_) + A_) * HW_;
    const float4* sc4 = (const float4*)sc;
    for (int i = tid; i < N_ / 4; i += 1024) {
        float4 s4 = sc4[i];
        atomicAdd(&LHIST[sb_bin(__float_as_uint(s4.x))], 1u);
        atomicAdd(&LHIST[sb_bin(__float_as_uint(s4.y))], 1u);
        atomicAdd(&LHIST[sb_bin(__float_as_uint(s4.z))], 1u);
        atomicAdd(&LHIST[sb_bin(__float_as_uint(s4.w))], 1u);
    }
    __syncthreads();

    // P2: in-place exclusive prefix (16 bins/thread, hierarchical shfl scan),
    //     active-bucket list, bin_hi (prefix monotone -> active bins = [0, bin_hi])
    {
        int base0 = tid * 16;
        unsigned int sum = 0;
        for (int q = 0; q < 16; ++q) sum += LHIST[base0 + q];
        unsigned int inc = sum;
#pragma unroll
        for (int off = 1; off < 64; off <<= 1) {
            unsigned int t = __shfl_up(inc, off);
            if (lane >= off) inc += t;
        }
        if (lane == 63) s_wsum[wid] = inc;
        __syncthreads();
        unsigned int wbase = 0;
        for (int wq = 0; wq < wid; ++wq) wbase += s_wsum[wq];
        unsigned int run = wbase + inc - sum;     // exclusive prefix of this thread's bins
        int mybinhi = -1;
        for (int q = 0; q < 16; ++q) {
            unsigned int c = LHIST[base0 + q];
            LHIST[base0 + q] = run;
            if (run < (unsigned int)PRE_) {
                mybinhi = base0 + q;
                if (c > 0) {
                    int pos = atomicAdd(&s_actn, 1);
                    if (pos < ACTMAX) {
                        s_aA[pos] = run;
                        s_aB[pos] = ((unsigned int)(base0 + q) << 16) | (c & 0xffffu);
                    }
                }
            }
            run += c;
        }
        if (mybinhi >= 0) atomicMax(&s_binhi, mybinhi);
    }
    __syncthreads();

    // P3: scatter keys of active bins to global slot ranges (arrival order)
    {
        int binhi = s_binhi;
        for (int i = tid; i < N_ / 4; i += 1024) {
            float4 s4 = sc4[i];
            float ss[4] = {s4.x, s4.y, s4.z, s4.w};
#pragma unroll
            for (int k2 = 0; k2 < 4; ++k2) {
                unsigned int sb = __float_as_uint(ss[k2]);
                int bin = sb_bin(sb);
                if (bin <= binhi) {
                    unsigned int slot = atomicAdd(&LHIST[bin], 1u);
                    if (slot < SKCAP) {
                        int i0 = i * 4 + k2;
                        int a = i0 / HW_, r = i0 - a * HW_;
                        unsigned int n = (unsigned int)(r * A_ + a);
                        skeys[b * SKCAP + slot] =
                            (((unsigned long long)(~sb)) << 32) | (unsigned long long)n;
                    }
                }
            }
        }
    }
    // export active-bucket list (written in P2; sync above orders it)
    int n = s_actn; if (n > ACTMAX) n = ACTMAX;
    for (int i = tid; i < n; i += 1024) {
        actA[b * ACTMAX + i] = s_aA[i];
        actB[b * ACTMAX + i] = s_aB[i];
    }
    if (tid == 0) actcnt[b] = (unsigned int)n;
}

// box decode exactly in the reference op order; no FMA contraction
__device__ __forceinline__ void compute_box(int b, unsigned int n,
                                            const float* __restrict__ deltas,
                                            const float* __restrict__ im_info,
                                            float box[4]) {
#pragma clang fp contract(off)
    int a   = (int)(n % A_);
    int pos = (int)(n / A_);
    int w   = pos % W_;
    int h   = pos / W_;
    float a0 = c_anchors[a][0] + (float)(w * 16);
    float a1 = c_anchors[a][1] + (float)(h * 16);
    float a2 = c_anchors[a][2] + (float)(w * 16);
    float a3 = c_anchors[a][3] + (float)(h * 16);
    float wa  = a2 - a0 + 1.f;
    float ha  = a3 - a1 + 1.f;
    float cxa = a0 + 0.5f * wa;
    float cya = a1 + 0.5f * ha;
    int base = ((b * 4 * A_ + a * 4) * H_ + h) * W_ + w;
    const int chs = HW_;
    float dx = deltas[base];
    float dy = deltas[base + chs];
    float dw = deltas[base + 2 * chs];
    float dh = deltas[base + 3 * chs];
    float pcx = dx * wa + cxa;
    float pcy = dy * ha + cya;
    float pw  = expf(dw) * wa;
    float ph  = expf(dh) * ha;
    float x1 = pcx - 0.5f * pw;
    float y1 = pcy - 0.5f * ph;
    float x2 = pcx + 0.5f * pw;
    float y2 = pcy + 0.5f * ph;
    float imh = im_info[b * 3 + 0], imw = im_info[b * 3 + 1];
    x1 = fminf(fmaxf(x1, 0.f), imw - 1.f);
    x2 = fminf(fmaxf(x2, 0.f), imw - 1.f);
    y1 = fminf(fmaxf(y1, 0.f), imh - 1.f);
    y2 = fminf(fmaxf(y2, 0.f), imh - 1.f);
    box[0] = x1; box[1] = y1; box[2] = x2; box[3] = y2;
}

// ---- kernel 2: per-bucket exact rank-by-counting + box decode into final sorted slot.
//      WIDE kernel (scattered delta gather needs chip-wide MLP), grid-stride buckets.
__global__ __launch_bounds__(256) void k_fixup(const unsigned long long* __restrict__ skeys,
                                               const unsigned int* __restrict__ actA,
                                               const unsigned int* __restrict__ actB,
                                               const unsigned int* __restrict__ actcnt,
                                               const float* __restrict__ deltas,
                                               const float* __restrict__ im_info,
                                               float* __restrict__ sboxes) {
    int b = blockIdx.y;
    unsigned int nact = actcnt[b];
    if (nact > ACTMAX) nact = ACTMAX;
    int tid = threadIdx.x;
    __shared__ unsigned long long lk[FXCAP];   // 16 KB
    float4* sb4 = (float4*)sboxes;
    for (unsigned int t = blockIdx.x; t < nact; t += FXGRID) {
        unsigned int start = actA[b * ACTMAX + t];
        unsigned int ab    = actB[b * ACTMAX + t];
        unsigned int cnt   = ab & 0xffffu;
        unsigned int m = cnt;
        if (start + m > SKCAP) m = SKCAP - start;
        if (m > FXCAP) m = FXCAP;
        for (unsigned int i = tid; i < m; i += 256) lk[i] = skeys[b * SKCAP + start + i];
        __syncthreads();
        for (unsigned int e = tid; e < m; e += 256) {
            unsigned long long k = lk[e];
            unsigned int r = 0;
            for (unsigned int i = 0; i < m; ++i) r += (lk[i] < k) ? 1u : 0u;
            unsigned int pos = start + r;
            if (pos < (unsigned int)PRE_) {
                unsigned int n = (unsigned int)(k & 0xffffffffull);
                float box[4];
                compute_box(b, n, deltas, im_info, box);
                sb4[b * PRE_ + pos] = make_float4(box[0], box[1], box[2], box[3]);
            }
        }
        __syncthreads();
    }
}

__device__ __forceinline__ bool iou_gt(float4 p, float pa, float4 q, float qa) {
    float iw = fminf(p.z, q.z) - fmaxf(p.x, q.x) + 1.f;
    float ih = fminf(p.w, q.w) - fmaxf(p.y, q.y) + 1.f;
    iw = fmaxf(iw, 0.f); ih = fmaxf(ih, 0.f);
    float inter = iw * ih;
    float iou = inter / ((pa + qa) - inter);
    return iou > 0.7f;
}

// ---- kernel 3: exact greedy NMS, pipelined (round-7 structure) with IN-LOOP mask
//      generation (round-15 proven) + phase-a ballot early-exit (sup2 is a monotone
//      OR: once all 64 lanes are suppressed, the rest of the kept-list scan is dead).
__global__ __launch_bounds__(1024) void k_nms(const float* __restrict__ sboxes,
                                              float* __restrict__ out) {
    int b = blockIdx.x;
    int tid = threadIdx.x;
    int lane = tid & 63;
    int wave = tid >> 6;                     // 0..15
    __shared__ float4 s_box[POST_ + 64];
    __shared__ float  s_ar [POST_ + 64];
    __shared__ unsigned long long s_pend[2][16];
    __shared__ unsigned long long s_mtile[3][64];   // triple-buffered mask tiles
    __shared__ int s_cnt[2];
    __shared__ int s_final;
    if (tid < 32) ((unsigned long long*)s_pend)[tid] = 0ull;
    if (tid < 2) s_cnt[tid] = 0;
    if (tid == 0) s_final = 0;

    const float4* bb = (const float4*)sboxes + b * PRE_;
    float* ob = out + b * POST_ * 5;

    // prologue: build mask tiles for blocks 0 (waves 0-7) and 1 (waves 8-15)
    {
        int blk01 = (wave < 8) ? 0 : 1;
        int wrel = wave & 7;
        float4 vb = bb[blk01 * 64 + lane];
        float ab = ((vb.z - vb.x) + 1.f) * ((vb.w - vb.y) + 1.f);
        for (int r = wrel * 8; r < wrel * 8 + 8; ++r) {
            float4 p;
            p.x = __shfl(vb.x, r); p.y = __shfl(vb.y, r);
            p.z = __shfl(vb.z, r); p.w = __shfl(vb.w, r);
            float pa = __shfl(ab, r);
            unsigned long long bal = __ballot((lane > r) && iou_gt(p, pa, vb, ab));
            if (lane == 0) s_mtile[blk01][r] = bal;
        }
    }
    // register prefetch: wave0 holds block 0; waves 1-15 hold block 1
    float4 vme;
    if (wave == 0) vme = bb[lane];
    else           vme = bb[64 + lane];
    __syncthreads();

    for (int k = 0; k < NB_; ++k) {
        int Cm1 = s_cnt[(k + 1) & 1];         // kept count through block k-1
        if (Cm1 >= POST_) break;
        if (wave == 0) {
            int idx = k * 64 + lane;
            bool valid = idx < PRE_;
            float4 v = vme;
            unsigned long long row = s_mtile[k % 3][lane];
            if (k + 1 < NB_) {                 // prefetch block k+1
                int nidx = (k + 1) * 64 + lane;
                vme = bb[nidx < PRE_ ? nidx : PRE_ - 1];
            }
            float area = ((v.z - v.x) + 1.f) * ((v.w - v.y) + 1.f);
            int Cm2 = s_cnt[k & 1];           // kept count through block k-2
            bool sup = !valid;
            int kk = Cm2;                      // delta: keeps added by block k-1
            for (; kk + 1 < Cm1; kk += 2) {
                float4 k0 = s_box[kk],   k1 = s_box[kk + 1];
                float  r0 = s_ar [kk],   r1 = s_ar [kk + 1];
                sup = sup | iou_gt(v, area, k0, r0) | iou_gt(v, area, k1, r1);
            }
            for (; kk < Cm1; ++kk)
                sup = sup | iou_gt(v, area, s_box[kk], s_ar[kk]);
            unsigned long long supm = __ballot(sup);
            const unsigned long long* pnd = s_pend[k & 1];
#pragma unroll
            for (int w2 = 1; w2 < 16; ++w2) supm |= pnd[w2];
            unsigned int rlo = (unsigned int)row;
            unsigned int rhi = (unsigned int)(row >> 32);
            unsigned long long alive = ~supm;
            unsigned long long keepm = 0ull;
            while (alive) {
                int i = __builtin_ctzll(alive);     // uniform across wave 0
                keepm |= (1ull << i);
                alive &= ~(1ull << i);
                unsigned long long mlo = (unsigned int)__builtin_amdgcn_readlane((int)rlo, i);
                unsigned long long mhi = (unsigned int)__builtin_amdgcn_readlane((int)rhi, i);
                alive &= ~((mhi << 32) | mlo);
            }
            if ((keepm >> lane) & 1ull) {
                int my = Cm1 + __builtin_popcountll(keepm & ((1ull << lane) - 1ull));
                s_box[my] = v;
                s_ar [my] = area;
                if (my < POST_) {
                    ob[my * 5 + 0] = (float)b;
                    ob[my * 5 + 1] = v.x; ob[my * 5 + 2] = v.y;
                    ob[my * 5 + 3] = v.z; ob[my * 5 + 4] = v.w;
                }
            }
            if (lane == 0) {
                int nc = Cm1 + __builtin_popcountll(keepm);
                s_cnt[k & 1] = nc;
                s_final = nc;
            }
        } else if (k + 1 < NB_) {
            // phase-a for block k+1 vs kept[0..Cm1), stride 15, unrolled x4,
            // ballot early-exit per batch (monotone OR -> exact)
            int jdx = (k + 1) * 64 + lane;
            bool valid2 = jdx < PRE_;
            float4 v2 = vme;
            if (k + 2 < NB_) {                 // prefetch block k+2
                int nj = (k + 2) * 64 + lane;
                vme = bb[nj < PRE_ ? nj : PRE_ - 1];
            }
            float area2 = ((v2.z - v2.x) + 1.f) * ((v2.w - v2.y) + 1.f);
            bool sup2 = !valid2;
            int kk = wave - 1;
            for (; kk + 45 < Cm1; kk += 60) {
                float4 k0 = s_box[kk],      k1 = s_box[kk + 15];
                float4 k2 = s_box[kk + 30], k3 = s_box[kk + 45];
                float  r0 = s_ar [kk],      r1 = s_ar [kk + 15];
                float  r2 = s_ar [kk + 30], r3 = s_ar [kk + 45];
                sup2 = sup2 | iou_gt(v2, area2, k0, r0) | iou_gt(v2, area2, k1, r1)
                            | iou_gt(v2, area2, k2, r2) | iou_gt(v2, area2, k3, r3);
                if (__ballot(!sup2) == 0ull) { kk = Cm1; break; }
            }
            for (; kk < Cm1; kk += 15)
                sup2 = sup2 | iou_gt(v2, area2, s_box[kk], s_ar[kk]);
            unsigned long long bal = __ballot(sup2);
            if (lane == 0) s_pend[(k + 1) & 1][wave] = bal;
            // build mask tile for block k+2 (vme holds its boxes) into slot (k+2)%3
            if (k + 2 < NB_) {
                float amex = ((vme.z - vme.x) + 1.f) * ((vme.w - vme.y) + 1.f);
                int slot = (k + 2) % 3;
                for (int r = wave - 1; r < 64; r += 15) {
                    float4 p;
                    p.x = __shfl(vme.x, r); p.y = __shfl(vme.y, r);
                    p.z = __shfl(vme.z, r); p.w = __shfl(vme.w, r);
                    float pa = __shfl(amex, r);
                    unsigned long long mb = __ballot((lane > r) && iou_gt(p, pa, vme, amex));
                    if (lane == 0) s_mtile[slot][r] = mb;
                }
            }
        }
        __syncthreads();
    }
    __syncthreads();
    int kept = s_final;
    int start = kept < POST_ ? kept : POST_;
    for (int r = start + tid; r < POST_; r += 1024) {
        ob[r * 5 + 0] = (float)b;
        ob[r * 5 + 1] = 0.f; ob[r * 5 + 2] = 0.f;
        ob[r * 5 + 3] = 0.f; ob[r * 5 + 4] = 0.f;
    }
}

extern "C" void kernel_launch(void* const* d_in, const int* in_sizes, int n_in,
                              void* d_out, int out_size, void* d_ws, size_t ws_size,
                              hipStream_t stream) {
    const float* scores  = (const float*)d_in[0];
    const float* deltas  = (const float*)d_in[1];
    const float* im_info = (const float*)d_in[2];
    float* out = (float*)d_out;

    char* ws = (char*)d_ws;
    unsigned long long* skeys  = (unsigned long long*)(ws);            // 262,144
    unsigned int*       actA   = (unsigned int*)      (ws + 262144);   //   4,096
    unsigned int*       actB   = (unsigned int*)      (ws + 266240);   //   4,096
    unsigned int*       actcnt = (unsigned int*)      (ws + 270336);   //      32
    float*              sbx    = (float*)             (ws + 270368);   // 384,000

    k_hps<<<B_, 1024, 0, stream>>>(scores, skeys, actA, actB, actcnt);
    dim3 fgrid(FXGRID, B_);
    k_fixup<<<fgrid, 256, 0, stream>>>(skeys, actA, actB, actcnt, deltas, im_info, sbx);
    k_nms<<<B_, 1024, 0, stream>>>(sbx, out);
}